// Round 1
// baseline (604.745 us; speedup 1.0000x reference)
//
#include <hip/hip_runtime.h>

// ---------- types ----------
typedef __attribute__((ext_vector_type(8))) short  s8v;    // 8 bf16 (as shorts) = 4 VGPR
typedef __attribute__((ext_vector_type(8))) unsigned short us8;
typedef __attribute__((ext_vector_type(4))) float  f4v;    // MFMA accumulator

// float -> bf16 round-to-nearest-even (inputs are finite; no NaN handling needed)
__device__ __forceinline__ unsigned short f2bf(float f) {
  unsigned int u = __builtin_bit_cast(unsigned int, f);
  u += 0x7fffu + ((u >> 16) & 1u);
  return (unsigned short)(u >> 16);
}

// async global->LDS, 16B per lane. LDS dest is wave-uniform base + lane*16;
// passing per-thread (base + tid*16) works because lane0's value is the wave base.
__device__ __forceinline__ void gll16(const void* g, void* l) {
  __builtin_amdgcn_global_load_lds(
      (const __attribute__((address_space(1))) unsigned int*)g,
      (__attribute__((address_space(3))) unsigned int*)l, 16, 0, 0);
}

// ---------- kernel 1: x fp32 -> bf16 ----------
// 33554432 elems, 8 per thread -> 4194304 threads
__global__ __launch_bounds__(256) void cast_bf16(const float* __restrict__ in,
                                                 unsigned short* __restrict__ out) {
  const size_t i = (size_t)blockIdx.x * 256 + threadIdx.x;
  const f4v* p = (const f4v*)in;
  f4v a = p[2 * i];
  f4v b = p[2 * i + 1];
  us8 r;
  r[0] = f2bf(a[0]); r[1] = f2bf(a[1]); r[2] = f2bf(a[2]); r[3] = f2bf(a[3]);
  r[4] = f2bf(b[0]); r[5] = f2bf(b[1]); r[6] = f2bf(b[2]); r[7] = f2bf(b[3]);
  *(us8*)&out[i * 8] = r;
}

// ---------- kernel 2: T[o1,i1,o2,i2,r2] = sum_r1 core0[o1,i1,r1]*core1[r1,o2,i2,r2] ----------
// T flat: ((o1*16+i1)*256 + (o2*16+i2))*64 + r2 ; total 4194304 floats
__global__ __launch_bounds__(256) void contract1(const float* __restrict__ c0,
                                                 const float* __restrict__ c1,
                                                 float* __restrict__ T) {
  const int idx = blockIdx.x * 256 + threadIdx.x;
  const int r2  = idx & 63;
  const int oi2 = (idx >> 6) & 255;   // o2*16+i2
  const int oi1 = idx >> 14;          // o1*16+i1
  const float* c0p = c0 + oi1 * 64;
  const float* c1p = c1 + oi2 * 64 + r2;  // + r1*16384
  float s = 0.f;
#pragma unroll 8
  for (int r1 = 0; r1 < 64; ++r1)
    s = fmaf(c0p[r1], c1p[r1 * 16384], s);
  T[idx] = s;
}

// ---------- kernel 3: W[out][in] = sum_r2 T[o1,i1,o2,i2,r2]*core2[r2,o3,i3], bf16 out ----------
// out = o1*256+o2*16+o3 ; in = i1*256+i2*16+i3 ; one thread does a full i3 row (16 outputs)
__global__ __launch_bounds__(256) void buildW(const float* __restrict__ T,
                                              const float* __restrict__ c2,
                                              unsigned short* __restrict__ W) {
  const int tid = blockIdx.x * 256 + threadIdx.x;   // 1048576 total
  const int i2  = tid & 15;
  const int i1  = (tid >> 4) & 15;
  const int out = tid >> 8;                         // 0..4095
  const int o3  = out & 15;
  const int o2  = (out >> 4) & 15;
  const int o1  = out >> 8;

  const float* Tp  = T + (size_t)(((o1 * 16 + i1) * 16 + o2) * 16 + i2) * 64;
  const float* c2p = c2 + o3 * 16;                  // + r2*256 + i3

  float acc[16];
#pragma unroll
  for (int j = 0; j < 16; ++j) acc[j] = 0.f;

  for (int r2 = 0; r2 < 64; ++r2) {
    const float t = Tp[r2];
    const f4v* cp = (const f4v*)(c2p + r2 * 256);
    f4v c0q = cp[0], c1q = cp[1], c2q = cp[2], c3q = cp[3];
#pragma unroll
    for (int j = 0; j < 4; ++j) acc[j]      = fmaf(t, c0q[j], acc[j]);
#pragma unroll
    for (int j = 0; j < 4; ++j) acc[4 + j]  = fmaf(t, c1q[j], acc[4 + j]);
#pragma unroll
    for (int j = 0; j < 4; ++j) acc[8 + j]  = fmaf(t, c2q[j], acc[8 + j]);
#pragma unroll
    for (int j = 0; j < 4; ++j) acc[12 + j] = fmaf(t, c3q[j], acc[12 + j]);
  }

  us8 w0, w1;
#pragma unroll
  for (int j = 0; j < 8; ++j) { w0[j] = f2bf(acc[j]); w1[j] = f2bf(acc[8 + j]); }
  unsigned short* dst = &W[(size_t)out * 4096 + i1 * 256 + i2 * 16];
  *(us8*)dst = w0;
  *((us8*)(dst + 8)) = w1;
}

// ---------- kernel 4: C[M,N] = A[M,K] * B[N,K]^T, bf16 in / fp32 out ----------
// m97 structure: 128x128 tile, BK=32, 4 waves (2x2), global_load_lds width 16,
// 16 MFMA(16x16x32 bf16) per K-step, 2 barriers per K-step.
#define BM 128
#define BN 128
#define BK 32

__global__ __launch_bounds__(256) void gemm_bt(const unsigned short* __restrict__ A,
                                               const unsigned short* __restrict__ B,
                                               float* __restrict__ C,
                                               int M, int N, int K) {
  __shared__ unsigned short sA[BM * BK];   // 8 KB
  __shared__ unsigned short sB[BN * BK];   // 8 KB

  const int tid  = threadIdx.x;
  const int lane = tid & 63;
  const int wid  = tid >> 6;
  const int wm   = wid >> 1;       // 0..1
  const int wn   = wid & 1;        // 0..1
  const long bm  = (long)blockIdx.y * BM;
  const long bn  = (long)blockIdx.x * BN;

  f4v acc[4][4];
#pragma unroll
  for (int m = 0; m < 4; ++m)
#pragma unroll
    for (int n = 0; n < 4; ++n) acc[m][n] = (f4v)0.0f;

  // staging: slot = tid (+256); row = slot>>2 (64B per row of 32 bf16), k-off = (slot&3)*8
  const int row0 = tid >> 2;
  const int ko   = (tid & 3) * 8;
  const unsigned short* gA0 = A + (bm + row0) * (size_t)K + ko;
  const unsigned short* gB0 = B + (bn + row0) * (size_t)K + ko;
  const size_t half = 64 * (size_t)K;      // rows 64..127
  unsigned short* lA0 = &sA[tid * 8];
  unsigned short* lA1 = &sA[2048 + tid * 8];
  unsigned short* lB0 = &sB[tid * 8];
  unsigned short* lB1 = &sB[2048 + tid * 8];

  const int fr = lane & 15;          // fragment row/col within 16
  const int fc = (lane >> 4) * 8;    // k offset within BK

  for (int kt = 0; kt < K; kt += BK) {
    gll16(gA0 + kt, lA0);
    gll16(gA0 + half + kt, lA1);
    gll16(gB0 + kt, lB0);
    gll16(gB0 + half + kt, lB1);
    __syncthreads();   // drains vmcnt -> LDS tiles ready

    s8v af[4], bfr[4];
#pragma unroll
    for (int m = 0; m < 4; ++m)
      af[m] = *(const s8v*)&sA[(wm * 64 + m * 16 + fr) * BK + fc];
#pragma unroll
    for (int n = 0; n < 4; ++n)
      bfr[n] = *(const s8v*)&sB[(wn * 64 + n * 16 + fr) * BK + fc];
#pragma unroll
    for (int m = 0; m < 4; ++m)
#pragma unroll
      for (int n = 0; n < 4; ++n)
        acc[m][n] = __builtin_amdgcn_mfma_f32_16x16x32_bf16(af[m], bfr[n], acc[m][n], 0, 0, 0);

    __syncthreads();   // protect LDS before next stage
  }

  // C/D layout (m89-verified): col = lane&15, row = (lane>>4)*4 + reg
  const long ccol0 = bn + wn * 64 + (lane & 15);
  const long crow0 = bm + wm * 64 + (lane >> 4) * 4;
#pragma unroll
  for (int m = 0; m < 4; ++m)
#pragma unroll
    for (int n = 0; n < 4; ++n)
#pragma unroll
      for (int r = 0; r < 4; ++r)
        C[(size_t)(crow0 + m * 16 + r) * N + ccol0 + n * 16] = acc[m][n][r];
}

// ---------- launch ----------
extern "C" void kernel_launch(void* const* d_in, const int* in_sizes, int n_in,
                              void* d_out, int out_size, void* d_ws, size_t ws_size,
                              hipStream_t stream) {
  const float* x  = (const float*)d_in[0];   // [8192,4096]
  const float* c0 = (const float*)d_in[1];   // [1,16,16,64]
  const float* c1 = (const float*)d_in[2];   // [64,16,16,64]
  const float* c2 = (const float*)d_in[3];   // [64,16,16,1]
  float* out = (float*)d_out;                // [8192,4096] fp32

  char* ws = (char*)d_ws;
  float*          T  = (float*)ws;                              // 16 MB
  unsigned short* Wb = (unsigned short*)(ws + (16u << 20));     // 32 MB  [out=4096][in=4096] bf16
  unsigned short* xb = (unsigned short*)(ws + (48u << 20));     // 64 MB  [8192][4096] bf16

  hipLaunchKernelGGL(cast_bf16, dim3(16384), dim3(256), 0, stream, x, xb);
  hipLaunchKernelGGL(contract1, dim3(16384), dim3(256), 0, stream, c0, c1, T);
  hipLaunchKernelGGL(buildW,    dim3(4096),  dim3(256), 0, stream, T, c2, Wb);
  hipLaunchKernelGGL(gemm_bt,   dim3(4096 / BN, 8192 / BM), dim3(256), 0, stream,
                     xb, Wb, out, 8192, 4096, 4096);
}

// Round 2
// 485.769 us; speedup vs baseline: 1.2449x; 1.2449x over previous
//
#include <hip/hip_runtime.h>

// ---------- types ----------
typedef __attribute__((ext_vector_type(8))) short  s8v;    // 8 bf16 (as shorts) = 4 VGPR
typedef __attribute__((ext_vector_type(8))) unsigned short us8;
typedef __attribute__((ext_vector_type(4))) float  f4v;    // MFMA accumulator

// float -> bf16 round-to-nearest-even (inputs are finite)
__device__ __forceinline__ unsigned short f2bf(float f) {
  unsigned int u = __builtin_bit_cast(unsigned int, f);
  u += 0x7fffu + ((u >> 16) & 1u);
  return (unsigned short)(u >> 16);
}

// async global->LDS, 16B per lane; per-thread dest is linear so wave base + lane*16 holds.
__device__ __forceinline__ void gll16(const void* g, void* l) {
  __builtin_amdgcn_global_load_lds(
      (const __attribute__((address_space(1))) unsigned int*)g,
      (__attribute__((address_space(3))) unsigned int*)l, 16, 0, 0);
}

// ---------- kernel 1: x fp32 -> bf16 ----------
__global__ __launch_bounds__(256) void cast_bf16(const float* __restrict__ in,
                                                 unsigned short* __restrict__ out) {
  const size_t i = (size_t)blockIdx.x * 256 + threadIdx.x;
  const f4v* p = (const f4v*)in;
  f4v a = p[2 * i];
  f4v b = p[2 * i + 1];
  us8 r;
  r[0] = f2bf(a[0]); r[1] = f2bf(a[1]); r[2] = f2bf(a[2]); r[3] = f2bf(a[3]);
  r[4] = f2bf(b[0]); r[5] = f2bf(b[1]); r[6] = f2bf(b[2]); r[7] = f2bf(b[3]);
  *(us8*)&out[i * 8] = r;
}

// ---------- kernel 2: T[o1,i1,o2,i2,r2] = sum_r1 core0[o1,i1,r1]*core1[r1,o2,i2,r2] ----------
__global__ __launch_bounds__(256) void contract1(const float* __restrict__ c0,
                                                 const float* __restrict__ c1,
                                                 float* __restrict__ T) {
  const int idx = blockIdx.x * 256 + threadIdx.x;
  const int r2  = idx & 63;
  const int oi2 = (idx >> 6) & 255;
  const int oi1 = idx >> 14;
  const float* c0p = c0 + oi1 * 64;
  const float* c1p = c1 + oi2 * 64 + r2;
  float s = 0.f;
#pragma unroll 8
  for (int r1 = 0; r1 < 64; ++r1)
    s = fmaf(c0p[r1], c1p[r1 * 16384], s);
  T[idx] = s;
}

// ---------- kernel 3: W[out][in] = sum_r2 T*core2, bf16 out ----------
__global__ __launch_bounds__(256) void buildW(const float* __restrict__ T,
                                              const float* __restrict__ c2,
                                              unsigned short* __restrict__ W) {
  const int tid = blockIdx.x * 256 + threadIdx.x;
  const int i2  = tid & 15;
  const int i1  = (tid >> 4) & 15;
  const int out = tid >> 8;
  const int o3  = out & 15;
  const int o2  = (out >> 4) & 15;
  const int o1  = out >> 8;

  const float* Tp  = T + (size_t)(((o1 * 16 + i1) * 16 + o2) * 16 + i2) * 64;
  const float* c2p = c2 + o3 * 16;

  float acc[16];
#pragma unroll
  for (int j = 0; j < 16; ++j) acc[j] = 0.f;

  for (int r2 = 0; r2 < 64; ++r2) {
    const float t = Tp[r2];
    const f4v* cp = (const f4v*)(c2p + r2 * 256);
    f4v c0q = cp[0], c1q = cp[1], c2q = cp[2], c3q = cp[3];
#pragma unroll
    for (int j = 0; j < 4; ++j) acc[j]      = fmaf(t, c0q[j], acc[j]);
#pragma unroll
    for (int j = 0; j < 4; ++j) acc[4 + j]  = fmaf(t, c1q[j], acc[4 + j]);
#pragma unroll
    for (int j = 0; j < 4; ++j) acc[8 + j]  = fmaf(t, c2q[j], acc[8 + j]);
#pragma unroll
    for (int j = 0; j < 4; ++j) acc[12 + j] = fmaf(t, c3q[j], acc[12 + j]);
  }

  us8 w0, w1;
#pragma unroll
  for (int j = 0; j < 8; ++j) { w0[j] = f2bf(acc[j]); w1[j] = f2bf(acc[8 + j]); }
  unsigned short* dst = &W[(size_t)out * 4096 + i1 * 256 + i2 * 16];
  *(us8*)dst = w0;
  *((us8*)(dst + 8)) = w1;
}

// ---------- kernel 4: 256x256-tile 8-phase GEMM, C = A * B^T ----------
// A[M][K], B[N][K] bf16, C[M][N] fp32. M=8192, N=4096, K=4096 (hardcoded).
// 8 waves (2M x 4N), BK=64 split in two K-halves; double-buffered LDS 128 KiB.
// LDS (ushort idx): A: buf*16384 + kh*8192 + row*32 + slot*8 ; B: +32768.
// Swizzle: 16B-slot ^= (row&3)  (read side); inverse applied on global source.

#define SBAR() do { asm volatile("" ::: "memory"); __builtin_amdgcn_s_barrier(); asm volatile("" ::: "memory"); } while (0)
#define VMW(N) asm volatile("s_waitcnt vmcnt(" #N ")" ::: "memory")

template<int MH>
__device__ __forceinline__ void mm16(f4v (&acc)[8][4], const s8v (&aF)[4], const s8v (&bF)[4]) {
  __builtin_amdgcn_s_setprio(1);
#pragma unroll
  for (int m = 0; m < 4; ++m)
#pragma unroll
    for (int n = 0; n < 4; ++n)
      acc[MH * 4 + m][n] =
          __builtin_amdgcn_mfma_f32_16x16x32_bf16(aF[m], bF[n], acc[MH * 4 + m][n], 0, 0, 0);
  __builtin_amdgcn_s_setprio(0);
}

__global__ __launch_bounds__(512, 2) void gemm8(const unsigned short* __restrict__ A,
                                                const unsigned short* __restrict__ B,
                                                float* __restrict__ C) {
  constexpr int M = 8192, N = 4096, K = 4096;
  constexpr int NT = K / 64;      // 64 K-tiles
  constexpr int NXT = N / 256;    // 16 tiles in N

  __shared__ unsigned short lds[65536];   // 128 KiB

  const int tid  = threadIdx.x;
  const int lane = tid & 63;
  const int wid  = tid >> 6;      // 0..7
  const int wm   = wid >> 2;      // 0..1
  const int wn   = wid & 3;       // 0..3

  // XCD-aware bijective swizzle (gridDim.x = 512, divisible by 8)
  const int cpx = (int)gridDim.x >> 3;
  const int wg  = ((int)blockIdx.x & 7) * cpx + ((int)blockIdx.x >> 3);
  const long bm = (long)(wg / NXT) * 256;
  const long bn = (long)(wg % NXT) * 256;

  // ---- staging addressing ----
  const int r0 = tid >> 2;                       // LDS row for j=0 issue
  const int sx = (tid & 3) ^ (r0 & 3);           // inverse-swizzled global 16B slot
  const unsigned short* gA = A + (bm + r0) * (size_t)K + sx * 8;
  const unsigned short* gB = B + (bn + r0) * (size_t)K + sx * 8;

#define STAGE(isB, kh, kn, nxt) do {                                             \
    const unsigned short* g_ = (isB ? gB : gA) + (kn) + (kh) * 32;               \
    unsigned short* l_ = &lds[(isB ? 32768 : 0) + (nxt) * 16384 + (kh) * 8192 + tid * 8]; \
    gll16(g_, l_);                                                               \
    gll16(g_ + 128 * (size_t)K, l_ + 4096);                                      \
  } while (0)

  // ---- fragment read addressing ----
  const int fr = lane & 15;
  const int ks = lane >> 4;                      // 0..3 (16B k-slot)
  const int swz = (ks ^ (fr & 3)) << 3;          // swizzled slot, ushort units
  const int aoff = (wm * 128 + fr) * 32 + swz;
  const int boff = (wn * 64 + fr) * 32 + swz;

#define RDA(mh, kh, cur) do {                                                    \
    const unsigned short* p_ = &lds[(cur) * 16384 + (kh) * 8192 + aoff + (mh) * 2048]; \
    aF[0] = *(const s8v*)(p_);        aF[1] = *(const s8v*)(p_ + 512);           \
    aF[2] = *(const s8v*)(p_ + 1024); aF[3] = *(const s8v*)(p_ + 1536);          \
  } while (0)
#define RDB(kh, cur) do {                                                        \
    const unsigned short* p_ = &lds[32768 + (cur) * 16384 + (kh) * 8192 + boff]; \
    bF[0] = *(const s8v*)(p_);        bF[1] = *(const s8v*)(p_ + 512);           \
    bF[2] = *(const s8v*)(p_ + 1024); bF[3] = *(const s8v*)(p_ + 1536);          \
  } while (0)

  f4v acc[8][4];
#pragma unroll
  for (int m = 0; m < 8; ++m)
#pragma unroll
    for (int n = 0; n < 4; ++n) acc[m][n] = (f4v)0.0f;

  // prologue: stage K-tile 0 into buf 0 (order: A-kh0, B-kh0, A-kh1, B-kh1)
  STAGE(0, 0, 0, 0);
  STAGE(1, 0, 0, 0);
  STAGE(0, 1, 0, 0);
  STAGE(1, 1, 0, 0);
  VMW(4);          // A-kh0 + B-kh0 landed; kh1 halves may fly
  SBAR();

  s8v aF[4], bF[4];
  for (int t = 0; t < NT; ++t) {
    const int cur = t & 1, nxt = cur ^ 1;
    const int kn = (t < NT - 1) ? (t + 1) * 64 : 0;   // wrap: harmless dummy prefetch
    // ---- p1 ----
    RDA(0, 0, cur); RDB(0, cur);
    STAGE(0, 0, kn, nxt);
    SBAR(); mm16<0>(acc, aF, bF); SBAR();
    // ---- p2 ----
    RDA(1, 0, cur);
    STAGE(1, 0, kn, nxt);
    VMW(4);        // A-kh1 + B-kh1 of current tile landed; this tile's 2 stages may fly
    SBAR(); mm16<1>(acc, aF, bF); SBAR();
    // ---- p3 ----
    RDA(0, 1, cur); RDB(1, cur);
    STAGE(0, 1, kn, nxt);
    SBAR(); mm16<0>(acc, aF, bF); SBAR();
    // ---- p4 ----
    RDA(1, 1, cur);
    STAGE(1, 1, kn, nxt);
    VMW(4);        // next tile's A-kh0 + B-kh0 landed; A-kh1/B-kh1 may fly
    SBAR(); mm16<1>(acc, aF, bF); SBAR();
  }
  asm volatile("s_waitcnt vmcnt(0)" ::: "memory");  // drain dummy prefetch before retire

  // ---- epilogue: C/D layout col = lane&15, row = (lane>>4)*4 + r ----
  const long crow0 = bm + wm * 128 + ks * 4;
  const long ccol0 = bn + wn * 64 + fr;
#pragma unroll
  for (int mf = 0; mf < 8; ++mf)
#pragma unroll
    for (int n = 0; n < 4; ++n)
#pragma unroll
      for (int r = 0; r < 4; ++r)
        C[(size_t)(crow0 + mf * 16 + r) * N + ccol0 + n * 16] = acc[mf][n][r];
#undef STAGE
#undef RDA
#undef RDB
}

// ---------- launch ----------
extern "C" void kernel_launch(void* const* d_in, const int* in_sizes, int n_in,
                              void* d_out, int out_size, void* d_ws, size_t ws_size,
                              hipStream_t stream) {
  const float* x  = (const float*)d_in[0];   // [8192,4096]
  const float* c0 = (const float*)d_in[1];   // [1,16,16,64]
  const float* c1 = (const float*)d_in[2];   // [64,16,16,64]
  const float* c2 = (const float*)d_in[3];   // [64,16,16,1]
  float* out = (float*)d_out;                // [8192,4096] fp32

  char* ws = (char*)d_ws;
  float*          T  = (float*)ws;                              // 16 MB
  unsigned short* Wb = (unsigned short*)(ws + (16u << 20));     // 32 MB  [out=4096][in=4096] bf16
  unsigned short* xb = (unsigned short*)(ws + (48u << 20));     // 64 MB  [8192][4096] bf16

  hipLaunchKernelGGL(cast_bf16, dim3(16384), dim3(256), 0, stream, x, xb);
  hipLaunchKernelGGL(contract1, dim3(16384), dim3(256), 0, stream, c0, c1, T);
  hipLaunchKernelGGL(buildW,    dim3(4096),  dim3(256), 0, stream, T, c2, Wb);
  hipLaunchKernelGGL(gemm8,     dim3(512),   dim3(512), 0, stream, xb, Wb, out);
}

// Round 3
// 377.201 us; speedup vs baseline: 1.6032x; 1.2878x over previous
//
#include <hip/hip_runtime.h>

// ---------- types ----------
typedef __attribute__((ext_vector_type(8))) short  s8v;    // 8 bf16 (as shorts) = 4 VGPR
typedef __attribute__((ext_vector_type(8))) unsigned short us8;
typedef __attribute__((ext_vector_type(4))) float  f4v;    // MFMA accumulator

// float -> bf16 round-to-nearest-even (inputs are finite)
__device__ __forceinline__ unsigned short f2bf(float f) {
  unsigned int u = __builtin_bit_cast(unsigned int, f);
  u += 0x7fffu + ((u >> 16) & 1u);
  return (unsigned short)(u >> 16);
}

// async global->LDS, 16B per lane; LDS dest must be linear (wave base + lane*16).
__device__ __forceinline__ void gll16(const void* g, void* l) {
  __builtin_amdgcn_global_load_lds(
      (const __attribute__((address_space(1))) unsigned int*)g,
      (__attribute__((address_space(3))) unsigned int*)l, 16, 0, 0);
}

// ---------- kernel 1: x fp32 -> bf16 ----------
__global__ __launch_bounds__(256) void cast_bf16(const float* __restrict__ in,
                                                 unsigned short* __restrict__ out) {
  const size_t i = (size_t)blockIdx.x * 256 + threadIdx.x;
  const f4v* p = (const f4v*)in;
  f4v a = p[2 * i];
  f4v b = p[2 * i + 1];
  us8 r;
  r[0] = f2bf(a[0]); r[1] = f2bf(a[1]); r[2] = f2bf(a[2]); r[3] = f2bf(a[3]);
  r[4] = f2bf(b[0]); r[5] = f2bf(b[1]); r[6] = f2bf(b[2]); r[7] = f2bf(b[3]);
  *(us8*)&out[i * 8] = r;
}

// ---------- kernel 2: T[o1,i1,o2,i2,r2] = sum_r1 core0[o1,i1,r1]*core1[r1,o2,i2,r2] ----------
__global__ __launch_bounds__(256) void contract1(const float* __restrict__ c0,
                                                 const float* __restrict__ c1,
                                                 float* __restrict__ T) {
  const int idx = blockIdx.x * 256 + threadIdx.x;
  const int r2  = idx & 63;
  const int oi2 = (idx >> 6) & 255;
  const int oi1 = idx >> 14;
  const float* c0p = c0 + oi1 * 64;
  const float* c1p = c1 + oi2 * 64 + r2;
  float s = 0.f;
#pragma unroll 8
  for (int r1 = 0; r1 < 64; ++r1)
    s = fmaf(c0p[r1], c1p[r1 * 16384], s);
  T[idx] = s;
}

// ---------- kernel 3: W build, LDS-staged ----------
// Block = (o1,o2): stage T-slice [256 ii][64 r2] (padded stride 65) + all of c2 into LDS.
// Thread (q=tid>>8, ii=tid&255) computes o3 = {q,4+q,8+q,12+q}, 16 i3 outputs each.
__global__ __launch_bounds__(1024) void buildW2(const float* __restrict__ T,
                                                const float* __restrict__ c2,
                                                unsigned short* __restrict__ W) {
  __shared__ float c2s[16384];      // 64 KB: [r2][o3][i3]
  __shared__ float Tl[16640];       // 65 KB: [ii=i1*16+i2][r2], stride 65 (2-way banks)

  const int tid = threadIdx.x;
  const int o1  = blockIdx.x >> 4;
  const int o2  = blockIdx.x & 15;

  // stage c2 (16384 floats, coalesced f4v)
#pragma unroll
  for (int j = 0; j < 4; ++j)
    ((f4v*)c2s)[j * 1024 + tid] = ((const f4v*)c2)[j * 1024 + tid];

  // stage T slice: for each i1, 1024 contiguous floats (i2,r2)
#pragma unroll
  for (int rr = 0; rr < 4; ++rr) {
    const int i1 = rr * 4 + (tid >> 8);
    const float* src = T + (size_t)(o1 * 16 + i1) * 16384 + o2 * 1024;
    const int c = tid & 255;
    f4v v = ((const f4v*)src)[c];
    float* dst = &Tl[(i1 * 16 + (c >> 4)) * 65 + (c & 15) * 4];
    dst[0] = v[0]; dst[1] = v[1]; dst[2] = v[2]; dst[3] = v[3];
  }
  __syncthreads();

  const int ii = tid & 255;
  const int i1 = ii >> 4, i2 = ii & 15;
#pragma unroll
  for (int k = 0; k < 4; ++k) {
    const int o3 = k * 4 + (tid >> 8);
    float acc[16];
#pragma unroll
    for (int j = 0; j < 16; ++j) acc[j] = 0.f;
    for (int r2 = 0; r2 < 64; ++r2) {
      const float t = Tl[ii * 65 + r2];
      const f4v* cp = (const f4v*)&c2s[r2 * 256 + o3 * 16];   // uniform -> broadcast
      f4v c0q = cp[0], c1q = cp[1], c2q = cp[2], c3q = cp[3];
#pragma unroll
      for (int j = 0; j < 4; ++j) acc[j]      = fmaf(t, c0q[j], acc[j]);
#pragma unroll
      for (int j = 0; j < 4; ++j) acc[4 + j]  = fmaf(t, c1q[j], acc[4 + j]);
#pragma unroll
      for (int j = 0; j < 4; ++j) acc[8 + j]  = fmaf(t, c2q[j], acc[8 + j]);
#pragma unroll
      for (int j = 0; j < 4; ++j) acc[12 + j] = fmaf(t, c3q[j], acc[12 + j]);
    }
    us8 w0, w1;
#pragma unroll
    for (int j = 0; j < 8; ++j) { w0[j] = f2bf(acc[j]); w1[j] = f2bf(acc[8 + j]); }
    unsigned short* dst =
        &W[(size_t)(o1 * 256 + o2 * 16 + o3) * 4096 + i1 * 256 + i2 * 16];
    *(us8*)dst = w0;
    *((us8*)(dst + 8)) = w1;
  }
}

// ---------- kernel 4: 256x256-tile 8-phase GEMM, C = A * B^T ----------
// A[M][K], B[N][K] bf16, C[M][N] fp32. M=8192, N=4096, K=4096 (hardcoded).
// LDS (ushort idx): A: buf*16384 + kh*8192 + row*32 + slot*8 ; B: +32768.
// Swizzle: 16B-slot ^= (row>>1)&3 — with the natural (row&1) bank offset this
// spreads each 16-lane read group across all 8 bank positions (2-way = free).
// Inverse applied on the global source of global_load_lds (rule #21).

#define SBAR() do { asm volatile("" ::: "memory"); __builtin_amdgcn_s_barrier(); asm volatile("" ::: "memory"); } while (0)
#define VMW(N) asm volatile("s_waitcnt vmcnt(" #N ")" ::: "memory")

template<int MH>
__device__ __forceinline__ void mm16(f4v (&acc)[8][4], const s8v (&aF)[4], const s8v (&bF)[4]) {
  __builtin_amdgcn_s_setprio(1);
#pragma unroll
  for (int m = 0; m < 4; ++m)
#pragma unroll
    for (int n = 0; n < 4; ++n)
      acc[MH * 4 + m][n] =
          __builtin_amdgcn_mfma_f32_16x16x32_bf16(aF[m], bF[n], acc[MH * 4 + m][n], 0, 0, 0);
  __builtin_amdgcn_s_setprio(0);
}

__global__ __launch_bounds__(512, 2) void gemm8(const unsigned short* __restrict__ A,
                                                const unsigned short* __restrict__ B,
                                                float* __restrict__ C) {
  constexpr int M = 8192, N = 4096, K = 4096;
  constexpr int NT = K / 64;      // 64 K-tiles
  constexpr int NXT = N / 256;    // 16 tiles in N

  __shared__ unsigned short lds[65536];   // 128 KiB

  const int tid  = threadIdx.x;
  const int lane = tid & 63;
  const int wid  = tid >> 6;      // 0..7
  const int wm   = wid >> 2;      // 0..1
  const int wn   = wid & 3;       // 0..3

  // XCD-aware bijective swizzle (gridDim.x = 512, divisible by 8)
  const int cpx = (int)gridDim.x >> 3;
  const int wg  = ((int)blockIdx.x & 7) * cpx + ((int)blockIdx.x >> 3);
  const long bm = (long)(wg / NXT) * 256;
  const long bn = (long)(wg % NXT) * 256;

  // ---- staging addressing ----
  const int r0 = tid >> 2;                        // LDS row for j=0 issue
  const int sx = (tid & 3) ^ ((r0 >> 1) & 3);     // inverse-swizzled global 16B slot
  const unsigned short* gA = A + (bm + r0) * (size_t)K + sx * 8;
  const unsigned short* gB = B + (bn + r0) * (size_t)K + sx * 8;

#define STAGE(isB, kh, kn, nxt) do {                                             \
    const unsigned short* g_ = (isB ? gB : gA) + (kn) + (kh) * 32;               \
    unsigned short* l_ = &lds[(isB ? 32768 : 0) + (nxt) * 16384 + (kh) * 8192 + tid * 8]; \
    gll16(g_, l_);                                                               \
    gll16(g_ + 128 * (size_t)K, l_ + 4096);                                      \
  } while (0)

  // ---- fragment read addressing ----
  const int fr = lane & 15;
  const int ks = lane >> 4;                       // 0..3 (16B k-slot)
  const int swz = (ks ^ ((fr >> 1) & 3)) << 3;    // swizzled slot, ushort units
  const int aoff = (wm * 128 + fr) * 32 + swz;
  const int boff = (wn * 64 + fr) * 32 + swz;

#define RDA(mh, kh, cur) do {                                                    \
    const unsigned short* p_ = &lds[(cur) * 16384 + (kh) * 8192 + aoff + (mh) * 2048]; \
    aF[0] = *(const s8v*)(p_);        aF[1] = *(const s8v*)(p_ + 512);           \
    aF[2] = *(const s8v*)(p_ + 1024); aF[3] = *(const s8v*)(p_ + 1536);          \
  } while (0)
#define RDB(kh, cur) do {                                                        \
    const unsigned short* p_ = &lds[32768 + (cur) * 16384 + (kh) * 8192 + boff]; \
    bF[0] = *(const s8v*)(p_);        bF[1] = *(const s8v*)(p_ + 512);           \
    bF[2] = *(const s8v*)(p_ + 1024); bF[3] = *(const s8v*)(p_ + 1536);          \
  } while (0)

  f4v acc[8][4];
#pragma unroll
  for (int m = 0; m < 8; ++m)
#pragma unroll
    for (int n = 0; n < 4; ++n) acc[m][n] = (f4v)0.0f;

  // prologue: stage K-tile 0 into buf 0 (order: A-kh0, B-kh0, A-kh1, B-kh1)
  STAGE(0, 0, 0, 0);
  STAGE(1, 0, 0, 0);
  STAGE(0, 1, 0, 0);
  STAGE(1, 1, 0, 0);
  VMW(4);          // A-kh0 + B-kh0 landed; kh1 halves may fly
  SBAR();

  s8v aF[4], bF[4];
  for (int t = 0; t < NT; ++t) {
    const int cur = t & 1, nxt = cur ^ 1;
    const int kn = (t < NT - 1) ? (t + 1) * 64 : 0;   // wrap: harmless dummy prefetch
    // ---- p1 ----
    RDA(0, 0, cur); RDB(0, cur);
    STAGE(0, 0, kn, nxt);
    SBAR(); mm16<0>(acc, aF, bF); SBAR();
    // ---- p2 ----
    RDA(1, 0, cur);
    STAGE(1, 0, kn, nxt);
    VMW(4);        // A-kh1 + B-kh1 of current tile landed; this tile's 2 stages may fly
    SBAR(); mm16<1>(acc, aF, bF); SBAR();
    // ---- p3 ----
    RDA(0, 1, cur); RDB(1, cur);
    STAGE(0, 1, kn, nxt);
    SBAR(); mm16<0>(acc, aF, bF); SBAR();
    // ---- p4 ----
    RDA(1, 1, cur);
    STAGE(1, 1, kn, nxt);
    VMW(4);        // next tile's A-kh0 + B-kh0 landed; A-kh1/B-kh1 may fly
    SBAR(); mm16<1>(acc, aF, bF); SBAR();
  }
  asm volatile("s_waitcnt vmcnt(0)" ::: "memory");  // drain dummy prefetch before retire

  // ---- epilogue: C/D layout col = lane&15, row = (lane>>4)*4 + r ----
  const long crow0 = bm + wm * 128 + ks * 4;
  const long ccol0 = bn + wn * 64 + fr;
#pragma unroll
  for (int mf = 0; mf < 8; ++mf)
#pragma unroll
    for (int n = 0; n < 4; ++n)
#pragma unroll
      for (int r = 0; r < 4; ++r)
        C[(size_t)(crow0 + mf * 16 + r) * N + ccol0 + n * 16] = acc[mf][n][r];
#undef STAGE
#undef RDA
#undef RDB
}

// ---------- launch ----------
extern "C" void kernel_launch(void* const* d_in, const int* in_sizes, int n_in,
                              void* d_out, int out_size, void* d_ws, size_t ws_size,
                              hipStream_t stream) {
  const float* x  = (const float*)d_in[0];   // [8192,4096]
  const float* c0 = (const float*)d_in[1];   // [1,16,16,64]
  const float* c1 = (const float*)d_in[2];   // [64,16,16,64]
  const float* c2 = (const float*)d_in[3];   // [64,16,16,1]
  float* out = (float*)d_out;                // [8192,4096] fp32

  char* ws = (char*)d_ws;
  float*          T  = (float*)ws;                              // 16 MB
  unsigned short* Wb = (unsigned short*)(ws + (16u << 20));     // 32 MB  [out=4096][in=4096] bf16
  unsigned short* xb = (unsigned short*)(ws + (48u << 20));     // 64 MB  [8192][4096] bf16

  hipLaunchKernelGGL(cast_bf16, dim3(16384), dim3(256), 0, stream, x, xb);
  hipLaunchKernelGGL(contract1, dim3(16384), dim3(256), 0, stream, c0, c1, T);
  hipLaunchKernelGGL(buildW2,   dim3(256),   dim3(1024), 0, stream, T, c2, Wb);
  hipLaunchKernelGGL(gemm8,     dim3(512),   dim3(512), 0, stream, xb, Wb, out);
}